// Round 12
// baseline (987.819 us; speedup 1.0000x reference)
//
#include <hip/hip_runtime.h>
#include <hip/hip_bf16.h>

#define NN 100000
#define NE 1000000
#define HD 64
#define NB 98                       // dst buckets of 1024 nodes
#define BSH 10
#define BCAP 12288                  // bin capacity (avg 10240, +20 sigma)
#define EPB 8192                    // edges per k_bin block
#define NB1 ((NE + EPB - 1) / EPB)  // 123
#define NSL 4                       // feature slabs (16 feats = 32 B rows)
#define RSTR NN                     // per-slab node stride (no dummy row needed)

typedef unsigned short u16;
typedef unsigned int u32;
typedef unsigned long long u64;
typedef unsigned int __attribute__((ext_vector_type(4))) u32x4;

__device__ __forceinline__ u16 f2b(float f) {
    __hip_bfloat16 h = __float2bfloat16(f);   // RNE
    return *reinterpret_cast<u16*>(&h);
}
__device__ __forceinline__ float uaf(u32 u) { return __uint_as_float(u); }

// ---------------- bucket sort (u32-packed bins): (dloc<<17)|src ----------------

__global__ void k_zero(int* __restrict__ bfill) {
    if (threadIdx.x < 128) bfill[threadIdx.x] = 0;
}

__global__ __launch_bounds__(256) void k_bin(const int* __restrict__ ei,
                                             int* __restrict__ bfill,
                                             u32* __restrict__ bins) {
    __shared__ int hist[NB];
    __shared__ int base[NB];
    int tid = threadIdx.x;
    for (int i = tid; i < NB; i += 256) hist[i] = 0;
    __syncthreads();
    int e0 = blockIdx.x * EPB;
    int n = min(EPB, NE - e0);
    for (int i = tid; i < n; i += 256)
        atomicAdd(&hist[ei[NE + e0 + i] >> BSH], 1);
    __syncthreads();
    for (int i = tid; i < NB; i += 256) {
        int c = hist[i];
        base[i] = c ? atomicAdd(&bfill[i], c) : 0;
        hist[i] = 0;
    }
    __syncthreads();
    for (int i = tid; i < n; i += 256) {
        int s = ei[e0 + i];
        int d = ei[NE + e0 + i];
        int g = d >> BSH;
        int pos = base[g] + atomicAdd(&hist[g], 1);
        bins[(size_t)g * BCAP + min(pos, BCAP - 1)] = ((u32)(d & 1023) << 17) | (u32)s;
    }
}

// ---------------- degree -> dis, pre-scaled x ----------------

__global__ __launch_bounds__(1024) void k_deg(const u32* __restrict__ bins,
        const int* __restrict__ bfill, const float2* __restrict__ x2,
        float* __restrict__ dis, float2* __restrict__ xs) {
    __shared__ int cnt[1024];
    int g = blockIdx.x, tid = threadIdx.x;
    cnt[tid] = 0;
    __syncthreads();
    int n = min(bfill[g], BCAP);
    const u32* bp = bins + (size_t)g * BCAP;
    for (int i = tid; i < n; i += 1024)
        atomicAdd(&cnt[bp[i] >> 17], 1);
    __syncthreads();
    int node = (g << BSH) + tid;
    if (node < NN) {
        float dd = rsqrtf((float)(cnt[tid] + 1));
        dis[node] = dd;
        float2 xv = x2[node];
        xs[node] = make_float2(xv.x * dd, xv.y * dd);
    }
}

// ---------------- layer 1: LDS scatter of xs, then in-block transform ----------------
// h layout (h1/h2/T): feat F of node n at byte ((F>>4)*RSTR + n)*32 + (F&15)*2
// invariant: stored rows pre-scaled by dis[src]

__global__ __launch_bounds__(1024) void k_l1s(const u32* __restrict__ bins,
        const int* __restrict__ bfill, const float2* __restrict__ xs,
        const float* __restrict__ dis, const float* __restrict__ W1,
        const float* __restrict__ b1, u16* __restrict__ h1) {
    __shared__ float accx[1024], accy[1024];
    __shared__ float W1s[2 * HD];
    __shared__ float b1s[HD];
    int g = blockIdx.x, tid = threadIdx.x;
    int node = (g << BSH) + tid;
    if (tid < 2 * HD) W1s[tid] = W1[tid];
    if (tid < HD) b1s[tid] = b1[tid];
    float2 self = (node < NN) ? xs[node] : make_float2(0.f, 0.f);
    accx[tid] = self.x;                     // self-loop init
    accy[tid] = self.y;
    __syncthreads();

    int n = min(bfill[g], BCAP);
    const u32* bp = bins + (size_t)g * BCAP;
    for (int i = tid; i < n; i += 1024) {
        u32 v = bp[i];
        int dloc = v >> 17;
        float2 xv = xs[v & 0x1ffff];
        atomicAdd(&accx[dloc], xv.x);
        atomicAdd(&accy[dloc], xv.y);
    }
    __syncthreads();

    if (node >= NN) return;
    float dd = dis[node];
    float ax = accx[tid] * dd, ay = accy[tid] * dd;
#pragma unroll
    for (int s = 0; s < NSL; ++s) {
        u32 pk[8];
#pragma unroll
        for (int j = 0; j < 8; ++j) {
            int f0 = s * 16 + 2 * j, f1 = f0 + 1;
            float o0 = fmaxf(fmaf(ax, W1s[f0], fmaf(ay, W1s[HD + f0], b1s[f0])), 0.f) * dd;
            float o1 = fmaxf(fmaf(ax, W1s[f1], fmaf(ay, W1s[HD + f1], b1s[f1])), 0.f) * dd;
            pk[j] = (u32)f2b(o0) | ((u32)f2b(o1) << 16);
        }
        char* hb = (char*)h1 + ((size_t)s * RSTR + node) * 32;
        u32x4 w0 = {pk[0], pk[1], pk[2], pk[3]};
        u32x4 w1 = {pk[4], pk[5], pk[6], pk[7]};
        *(u32x4*)hb = w0;
        *(u32x4*)(hb + 16) = w1;
    }
}

// ---------------- transform: T = h @ W (both slab-major bf16) ----------------

__global__ __launch_bounds__(256) void k_xf(const u16* __restrict__ hin,
        const float* __restrict__ W, u16* __restrict__ T) {
    int tid = threadIdx.x, lane = tid & 63, wv = tid >> 6;
    int n0 = blockIdx.x * 16 + wv * 4;
    int node = n0 + (lane >> 4);
    int fl = lane & 15;
    u64 v = *(const u64*)((const char*)hin +
            ((size_t)((fl >> 2) * RSTR + node) * 32 + (size_t)(fl & 3) * 8));
    u32 lo = (u32)v, hi = (u32)(v >> 32);
    float hv[4] = { uaf(lo << 16), uaf(lo & 0xffff0000u), uaf(hi << 16), uaf(hi & 0xffff0000u) };
    float o[4] = {0.f, 0.f, 0.f, 0.f};
#pragma unroll
    for (int k = 0; k < HD; ++k) {
        float wk = W[k * HD + lane];
#pragma unroll
        for (int q = 0; q < 4; ++q) {
            float a = __int_as_float(__builtin_amdgcn_readlane(
                __float_as_int(hv[k & 3]), q * 16 + (k >> 2)));
            o[q] = fmaf(a, wk, o[q]);
        }
    }
#pragma unroll
    for (int q = 0; q < 4; ++q)
        *(u16*)((char*)T + ((size_t)((lane >> 4) * RSTR + n0 + q) * 32 + (lane & 15) * 2)) = f2b(o[q]);
}

// ---------------- aggregation: LDS-accumulator scatter ----------------
// block = (bucket g, slab s); acc[1024][16] f32 in LDS (64 KB, 2 blocks/CU).
// init acc = own T rows (self-loop, pre-scaled); edge task = 8 lanes/edge,
// each lane: 4 B of T[src] + 2 LDS atomicAdd. Writeback coalesced.
// !LAST: hout = bf16(relu(dd*acc+b)*dd). LAST: partial = relu(dd*acc+b)@Wl_slice

template <bool LAST>
__global__ __launch_bounds__(512) void k_aggs(const u16* __restrict__ T,
        const u32* __restrict__ bins, const int* __restrict__ bfill,
        const float* __restrict__ dis, const float* __restrict__ b,
        const float* __restrict__ Wl, u16* __restrict__ hout,
        float* __restrict__ partial) {
    __shared__ float acc[1024 * 16];        // 64 KB
    int bid = blockIdx.x;
    int g = bid >> 2, slab = bid & 3;       // blockIdx&3: slab per-XCD stable under RR
    int tid = threadIdx.x;
    const char* Tb = (const char*)T + (size_t)slab * RSTR * 32;
    int nodebase = g << BSH;

    // init from own T rows (coalesced 32 KB read)
#pragma unroll
    for (int k = 0; k < 16; ++k) {
        int task = k * 512 + tid;           // 8192: nd = task>>3, u32-index u = task&7
        int nd = task >> 3, u = task & 7;
        int node = nodebase + nd;
        u32 w = (node < NN) ? *(const u32*)(Tb + (size_t)node * 32 + u * 4) : 0u;
        acc[nd * 16 + 2 * u]     = uaf(w << 16);
        acc[nd * 16 + 2 * u + 1] = uaf(w & 0xffff0000u);
    }
    __syncthreads();

    int n = min(bfill[g], BCAP);
    const u32* bp = bins + (size_t)g * BCAP;
    int ntask = n << 3;                     // 8 lane-tasks per edge
#pragma unroll 4
    for (int t = tid; t < ntask; t += 512) {
        int e = t >> 3, j = t & 7;
        u32 v = bp[e];                      // 8 lanes broadcast-load same entry
        int dloc = v >> 17;
        u32 w = *(const u32*)(Tb + (size_t)(v & 0x1ffff) * 32 + j * 4);
        atomicAdd(&acc[dloc * 16 + 2 * j],     uaf(w << 16));
        atomicAdd(&acc[dloc * 16 + 2 * j + 1], uaf(w & 0xffff0000u));
    }
    __syncthreads();

    // writeback: 2 nodes per thread
#pragma unroll
    for (int k = 0; k < 2; ++k) {
        int nd = k * 512 + tid;
        int node = nodebase + nd;
        if (node >= NN) continue;
        float dd = dis[node];
        if (!LAST) {
            u32 pk[8];
#pragma unroll
            for (int j = 0; j < 8; ++j) {
                float o0 = fmaxf(fmaf(dd, acc[nd * 16 + 2 * j],     b[slab * 16 + 2 * j]),     0.f) * dd;
                float o1 = fmaxf(fmaf(dd, acc[nd * 16 + 2 * j + 1], b[slab * 16 + 2 * j + 1]), 0.f) * dd;
                pk[j] = (u32)f2b(o0) | ((u32)f2b(o1) << 16);
            }
            char* hb = (char*)hout + ((size_t)slab * RSTR + node) * 32;
            u32x4 w0 = {pk[0], pk[1], pk[2], pk[3]};
            u32x4 w1 = {pk[4], pk[5], pk[6], pk[7]};
            *(u32x4*)hb = w0;
            *(u32x4*)(hb + 16) = w1;
        } else {
            float ps = 0.f;
#pragma unroll
            for (int j = 0; j < 16; ++j)
                ps = fmaf(fmaxf(fmaf(dd, acc[nd * 16 + j], b[slab * 16 + j]), 0.f),
                          Wl[slab * 16 + j], ps);
            partial[(size_t)slab * NN + node] = ps;
        }
    }
}

// ---------------- final: y = sum of 4 slab partials + bl ----------------

__global__ __launch_bounds__(256) void k_fin(const float* __restrict__ partial,
        const float* __restrict__ bl, float* __restrict__ y) {
    int i = blockIdx.x * 256 + threadIdx.x;
    if (i >= NN) return;
    y[i] = partial[i] + partial[NN + i] + partial[2 * NN + i] + partial[3 * NN + i] + bl[0];
}

// ---------------- launch ----------------

extern "C" void kernel_launch(void* const* d_in, const int* in_sizes, int n_in,
                              void* d_out, int out_size, void* d_ws, size_t ws_size,
                              hipStream_t stream) {
    const float* x  = (const float*)d_in[0];
    const int*   ei = (const int*)d_in[1];   // [2,E]: src = ei[0:E], dst = ei[E:2E]
    const float* W1 = (const float*)d_in[2];
    const float* b1 = (const float*)d_in[3];
    const float* W2 = (const float*)d_in[4];
    const float* b2 = (const float*)d_in[5];
    const float* W3 = (const float*)d_in[6];
    const float* b3 = (const float*)d_in[7];
    const float* Wl = (const float*)d_in[8];
    const float* bl = (const float*)d_in[9];

    // workspace layout, 64 B aligned chunks
    char* p = (char*)d_ws;
    auto alloc = [&](size_t bytes) { char* r = p; p += (bytes + 63) & ~63ull; return r; };
    u32*    bins   = (u32*)   alloc((size_t)NB * BCAP * 4);   // 4.8 MB
    int*    bfill  = (int*)   alloc(128 * 4);
    float*  dis    = (float*) alloc(NN * 4);
    float2* xs     = (float2*)alloc(NN * 8);
    u16*    h1     = (u16*)   alloc((size_t)NSL * RSTR * 16 * 2);   // 12.8 MB
    u16*    h2     = (u16*)   alloc((size_t)NSL * RSTR * 16 * 2);
    u16*    T      = (u16*)   alloc((size_t)NSL * RSTR * 16 * 2);
    float*  partial= (float*) alloc((size_t)NSL * NN * 4);

    k_zero<<<1, 128, 0, stream>>>(bfill);
    k_bin <<<NB1, 256, 0, stream>>>(ei, bfill, bins);
    k_deg <<<NB, 1024, 0, stream>>>(bins, bfill, (const float2*)x, dis, xs);
    k_l1s <<<NB, 1024, 0, stream>>>(bins, bfill, xs, dis, W1, b1, h1);

    k_xf  <<<NN / 16, 256, 0, stream>>>(h1, W2, T);
    k_aggs<false><<<NB * NSL, 512, 0, stream>>>(T, bins, bfill, dis, b2, nullptr, h2, nullptr);

    k_xf  <<<NN / 16, 256, 0, stream>>>(h2, W3, T);
    k_aggs<true ><<<NB * NSL, 512, 0, stream>>>(T, bins, bfill, dis, b3, Wl, nullptr, partial);

    k_fin<<<(NN + 255) / 256, 256, 0, stream>>>(partial, bl, (float*)d_out);
}

// Round 13
// 199.675 us; speedup vs baseline: 4.9471x; 4.9471x over previous
//
#include <hip/hip_runtime.h>
#include <hip/hip_bf16.h>

#define NN 100000
#define NE 1000000
#define HD 64
#define NB 98                       // dst buckets of 1024 nodes
#define BSH 10
#define BCAP 12288                  // bin capacity (avg 10240, +20 sigma)
#define EPB 8192                    // edges per k_bin block
#define NB1 ((NE + EPB - 1) / EPB)  // 123
#define NSL 8                       // feature slabs (8 feats = 16 B rows; 1.6 MB/slab)
#define RSTR (NN + 1)               // per-slab row stride (row NN = dummy zeros)
#define BCAPP 4096                  // per-bucket pad slack
#define NAGGB ((NN + 255) / 256)    // 391
#define NAGG (NSL * NAGGB)          // 3128

typedef unsigned short u16;
typedef unsigned int u32;
typedef unsigned long long u64;
typedef unsigned int __attribute__((ext_vector_type(4))) u32x4;

__device__ __forceinline__ u16 f2b(float f) {
    __hip_bfloat16 h = __float2bfloat16(f);   // RNE
    return *reinterpret_cast<u16*>(&h);
}
__device__ __forceinline__ float uaf(u32 u) { return __uint_as_float(u); }
__device__ __forceinline__ void acc8(float* a, uint4 v) {
    a[0] += uaf(v.x << 16); a[1] += uaf(v.x & 0xffff0000u);
    a[2] += uaf(v.y << 16); a[3] += uaf(v.y & 0xffff0000u);
    a[4] += uaf(v.z << 16); a[5] += uaf(v.z & 0xffff0000u);
    a[6] += uaf(v.w << 16); a[7] += uaf(v.w & 0xffff0000u);
}

// ---------------- CSR build: bucketed counting sort (u32-packed bins) ----------------

__global__ __launch_bounds__(256) void k_bin(const int* __restrict__ ei,
                                             int* __restrict__ bfill,
                                             u32* __restrict__ bins) {
    __shared__ int hist[NB];
    __shared__ int base[NB];
    int tid = threadIdx.x;
    for (int i = tid; i < NB; i += 256) hist[i] = 0;
    __syncthreads();
    int e0 = blockIdx.x * EPB;
    int n = min(EPB, NE - e0);
    for (int i = tid; i < n; i += 256)
        atomicAdd(&hist[ei[NE + e0 + i] >> BSH], 1);
    __syncthreads();
    for (int i = tid; i < NB; i += 256) {
        int c = hist[i];
        base[i] = c ? atomicAdd(&bfill[i], c) : 0;
        hist[i] = 0;
    }
    __syncthreads();
    for (int i = tid; i < n; i += 256) {
        int s = ei[e0 + i];
        int d = ei[NE + e0 + i];
        int g = d >> BSH;
        int pos = base[g] + atomicAdd(&hist[g], 1);
        bins[(size_t)g * BCAP + min(pos, BCAP - 1)] = ((u32)(d & 1023) << 17) | (u32)s;
    }
}

// per bucket: rowptr (x4-aligned, padded rows), plen, self-loop+pads, dis, xs,
// XCD-local edge scatter, T dummy-row zeroing. col stores src INDEX (pad = NN).
__global__ __launch_bounds__(1024) void k_build(const u32* __restrict__ bins,
        const int* __restrict__ bfill,
        int* __restrict__ rowptr, int* __restrict__ plen, int* __restrict__ col,
        const float2* __restrict__ x2, float* __restrict__ dis,
        float2* __restrict__ xs, u16* __restrict__ T) {
    __shared__ int cnt[1024];
    __shared__ int rof[1024];
    __shared__ int wsum[16];
    __shared__ int gbase_sh;
    int g = blockIdx.x, tid = threadIdx.x;
    int lane = tid & 63, w = tid >> 6;

    // bucket base = sum_{t<g} (align4(bfill[t]) + BCAPP)   (x4-aligned)
    int part = (tid < g) ? (((bfill[tid] + 3) & ~3) + BCAPP) : 0;
#pragma unroll
    for (int off = 32; off; off >>= 1) part += __shfl_xor(part, off);
    if (lane == 0) wsum[w] = part;
    cnt[tid] = 0;
    __syncthreads();
    if (tid == 0) {
        int s = 0;
#pragma unroll
        for (int i = 0; i < 16; ++i) s += wsum[i];
        gbase_sh = s;
    }
    __syncthreads();
    int gbase = gbase_sh;

    int n = min(bfill[g], BCAP);
    const u32* bp = bins + (size_t)g * BCAP;
    for (int i = tid; i < n; i += 1024)
        atomicAdd(&cnt[bp[i] >> 17], 1);
    __syncthreads();

    int node = (g << BSH) + tid;
    int c = cnt[tid];
    int pc = (node < NN) ? ((c + 1 + 3) & ~3) : 0;   // row len padded to x4

    int s = pc;
#pragma unroll
    for (int off = 1; off < 64; off <<= 1) { int t = __shfl_up(s, off); if (lane >= off) s += t; }
    if (lane == 63) wsum[w] = s;
    __syncthreads();
    if (tid < 16) {
        int ws = wsum[tid];
#pragma unroll
        for (int off = 1; off < 16; off <<= 1) { int t = __shfl_up(ws, off); if (tid >= off) ws += t; }
        wsum[tid] = ws;
    }
    __syncthreads();
    int r = gbase + (w ? wsum[w - 1] : 0) + s - pc;
    rof[tid] = r;
    if (node < NN) {
        rowptr[node] = r;
        plen[node] = pc;
        col[r] = node;                          // self-loop at slot 0
        for (int t = c + 1; t < pc; ++t) col[r + t] = NN;   // pads -> dummy row
        float dd = rsqrtf((float)(c + 1));
        dis[node] = dd;
        float2 xv = x2[node];
        xs[node] = make_float2(xv.x * dd, xv.y * dd);
    }
    cnt[tid] = 1;                               // fill counter (slot 0 taken)
    __syncthreads();

    for (int i = tid; i < n; i += 1024) {
        u32 v = bp[i];
        int dloc = v >> 17;
        int src = (int)(v & 0x1ffffu);
        int local = atomicAdd(&cnt[dloc], 1);
        col[rof[dloc] + local] = src;
    }

    if (g == 0) {
        // zero dummy row NN of each of the 8 slabs of T (16 B each)
        if (tid < NSL * 8) T[((size_t)(tid >> 3) * RSTR + NN) * 8 + (tid & 7)] = 0;
        if (tid == 0) xs[NN] = make_float2(0.f, 0.f);
    }
}

// ---------------- layer 1: lane-per-node gather of xs, then transform ----------------
// h layout (h1/h2/T): feat F of node n at byte ((F>>3)*RSTR + n)*16 + (F&7)*2
// invariant: stored rows pre-scaled by dis[src]

__global__ __launch_bounds__(256) void k_l1(const float2* __restrict__ xs,
        const int* __restrict__ rowptr, const int* __restrict__ plen,
        const int* __restrict__ col,
        const float* __restrict__ dis, const float* __restrict__ W1,
        const float* __restrict__ b1, u16* __restrict__ h1) {
    int node = blockIdx.x * 256 + threadIdx.x;
    if (node >= NN) return;
    int r = rowptr[node], pl = plen[node];
    float ax = 0.f, ay = 0.f;
    for (int i = 0; i < pl; i += 4) {
        int4 c = *(const int4*)(col + r + i);
        float2 v0 = xs[c.x], v1 = xs[c.y], v2 = xs[c.z], v3 = xs[c.w];
        ax += (v0.x + v1.x) + (v2.x + v3.x);
        ay += (v0.y + v1.y) + (v2.y + v3.y);
    }
    float dd = dis[node];
    ax *= dd; ay *= dd;
#pragma unroll
    for (int s = 0; s < NSL; ++s) {            // W1/b1 wave-uniform -> scalar loads
        u32 pk[4];
#pragma unroll
        for (int j = 0; j < 4; ++j) {
            int f0 = s * 8 + 2 * j, f1 = f0 + 1;
            float o0 = fmaxf(fmaf(ax, W1[f0], fmaf(ay, W1[HD + f0], b1[f0])), 0.f) * dd;
            float o1 = fmaxf(fmaf(ax, W1[f1], fmaf(ay, W1[HD + f1], b1[f1])), 0.f) * dd;
            pk[j] = (u32)f2b(o0) | ((u32)f2b(o1) << 16);
        }
        u32x4 wv = {pk[0], pk[1], pk[2], pk[3]};
        *(u32x4*)((char*)h1 + ((size_t)s * RSTR + node) * 16) = wv;   // coalesced
    }
}

// ---------------- transform: T = h @ W (both 8-slab-major bf16) ----------------
// wave = 4 nodes; lane reads ONE u64 (4 feats): feats 4*fl..4*fl+3 of node n0+(lane>>4)
// at byte ((fl>>1)*RSTR + node)*16 + (fl&1)*8. Output feat F=lane for the 4 nodes.

__global__ __launch_bounds__(256) void k_xf(const u16* __restrict__ hin,
        const float* __restrict__ W, u16* __restrict__ T) {
    int tid = threadIdx.x, lane = tid & 63, wv = tid >> 6;
    int n0 = blockIdx.x * 16 + wv * 4;
    int node = n0 + (lane >> 4);
    int fl = lane & 15;
    u64 v = *(const u64*)((const char*)hin +
            ((size_t)((fl >> 1) * RSTR + node) * 16 + (size_t)(fl & 1) * 8));
    u32 lo = (u32)v, hi = (u32)(v >> 32);
    float hv[4] = { uaf(lo << 16), uaf(lo & 0xffff0000u), uaf(hi << 16), uaf(hi & 0xffff0000u) };
    float o[4] = {0.f, 0.f, 0.f, 0.f};
#pragma unroll
    for (int k = 0; k < HD; ++k) {
        float wk = W[k * HD + lane];
#pragma unroll
        for (int q = 0; q < 4; ++q) {
            float a = __int_as_float(__builtin_amdgcn_readlane(
                __float_as_int(hv[k & 3]), q * 16 + (k >> 2)));
            o[q] = fmaf(a, wk, o[q]);
        }
    }
#pragma unroll
    for (int q = 0; q < 4; ++q)
        *(u16*)((char*)T + ((size_t)(lane >> 3) * RSTR + n0 + q) * 16 + (lane & 7) * 2) = f2b(o[q]);
}

// ---------------- slab aggregation: lane-per-node gather, 1.6 MB L2-resident slab ----
// slab = blockIdx&7 -> natural round-robin pins slab s to XCD s (perf heuristic only).
// Padded-x4 CSR: col for 8 edges = two int4 loads; 8 independent uint4 row-gathers.

template <bool LAST>
__global__ __launch_bounds__(256) void k_agg(const u16* __restrict__ T,
        const int* __restrict__ rowptr, const int* __restrict__ plen,
        const int* __restrict__ col,
        const float* __restrict__ dis, const float* __restrict__ b,
        const float* __restrict__ Wl, u16* __restrict__ hout,
        float* __restrict__ partial) {
    int slab = blockIdx.x & 7;
    int node = (blockIdx.x >> 3) * 256 + threadIdx.x;
    if (node >= NN) return;
    const char* Tb = (const char*)T + (size_t)slab * RSTR * 16;

    int r = rowptr[node];
    int pl = plen[node];                 // multiple of 4, >= 4
    float acc[8];
#pragma unroll
    for (int j = 0; j < 8; ++j) acc[j] = 0.f;

    int i = 0;
    for (; i + 8 <= pl; i += 8) {
        int4 c0 = *(const int4*)(col + r + i);
        int4 c1 = *(const int4*)(col + r + i + 4);
        uint4 v0 = *(const uint4*)(Tb + (size_t)c0.x * 16);
        uint4 v1 = *(const uint4*)(Tb + (size_t)c0.y * 16);
        uint4 v2 = *(const uint4*)(Tb + (size_t)c0.z * 16);
        uint4 v3 = *(const uint4*)(Tb + (size_t)c0.w * 16);
        uint4 v4 = *(const uint4*)(Tb + (size_t)c1.x * 16);
        uint4 v5 = *(const uint4*)(Tb + (size_t)c1.y * 16);
        uint4 v6 = *(const uint4*)(Tb + (size_t)c1.z * 16);
        uint4 v7 = *(const uint4*)(Tb + (size_t)c1.w * 16);
        acc8(acc, v0); acc8(acc, v1); acc8(acc, v2); acc8(acc, v3);
        acc8(acc, v4); acc8(acc, v5); acc8(acc, v6); acc8(acc, v7);
    }
    if (i < pl) {                        // exactly 4 remain
        int4 c0 = *(const int4*)(col + r + i);
        uint4 v0 = *(const uint4*)(Tb + (size_t)c0.x * 16);
        uint4 v1 = *(const uint4*)(Tb + (size_t)c0.y * 16);
        uint4 v2 = *(const uint4*)(Tb + (size_t)c0.z * 16);
        uint4 v3 = *(const uint4*)(Tb + (size_t)c0.w * 16);
        acc8(acc, v0); acc8(acc, v1); acc8(acc, v2); acc8(acc, v3);
    }

    float dd = dis[node];
    if (!LAST) {
        u32 pk[4];
#pragma unroll
        for (int j = 0; j < 4; ++j) {
            float o0 = fmaxf(fmaf(dd, acc[2 * j],     b[slab * 8 + 2 * j]),     0.f) * dd;
            float o1 = fmaxf(fmaf(dd, acc[2 * j + 1], b[slab * 8 + 2 * j + 1]), 0.f) * dd;
            pk[j] = (u32)f2b(o0) | ((u32)f2b(o1) << 16);
        }
        u32x4 wv = {pk[0], pk[1], pk[2], pk[3]};
        *(u32x4*)((char*)hout + ((size_t)slab * RSTR + node) * 16) = wv;   // coalesced
    } else {
        float ps = 0.f;
#pragma unroll
        for (int j = 0; j < 8; ++j)
            ps = fmaf(fmaxf(fmaf(dd, acc[j], b[slab * 8 + j]), 0.f),
                      Wl[slab * 8 + j], ps);
        partial[(size_t)slab * NN + node] = ps;
    }
}

// ---------------- final: y = sum of 8 slab partials + bl ----------------

__global__ __launch_bounds__(256) void k_fin(const float* __restrict__ partial,
        const float* __restrict__ bl, float* __restrict__ y) {
    int i = blockIdx.x * 256 + threadIdx.x;
    if (i >= NN) return;
    float s = bl[0];
#pragma unroll
    for (int k = 0; k < NSL; ++k) s += partial[(size_t)k * NN + i];
    y[i] = s;
}

// ---------------- launch ----------------

extern "C" void kernel_launch(void* const* d_in, const int* in_sizes, int n_in,
                              void* d_out, int out_size, void* d_ws, size_t ws_size,
                              hipStream_t stream) {
    const float* x  = (const float*)d_in[0];
    const int*   ei = (const int*)d_in[1];   // [2,E]: src = ei[0:E], dst = ei[E:2E]
    const float* W1 = (const float*)d_in[2];
    const float* b1 = (const float*)d_in[3];
    const float* W2 = (const float*)d_in[4];
    const float* b2 = (const float*)d_in[5];
    const float* W3 = (const float*)d_in[6];
    const float* b3 = (const float*)d_in[7];
    const float* Wl = (const float*)d_in[8];
    const float* bl = (const float*)d_in[9];

    // workspace layout, 64 B aligned chunks
    char* p = (char*)d_ws;
    auto alloc = [&](size_t bytes) { char* r = p; p += (bytes + 63) & ~63ull; return r; };
    u32*    bins   = (u32*)   alloc((size_t)NB * BCAP * 4);   // 4.8 MB
    int*    bfill  = (int*)   alloc(128 * 4);
    int*    rowptr = (int*)   alloc((NN + 2) * 4);
    int*    plen   = (int*)   alloc((NN + 2) * 4);
    float*  dis    = (float*) alloc(NN * 4);
    int*    col    = (int*)   alloc((size_t)(NE + NB * BCAPP + 256) * 4);  // 5.6 MB
    float2* xs     = (float2*)alloc((NN + 1) * 8);
    u16*    h1     = (u16*)   alloc((size_t)NSL * RSTR * 8 * 2);   // 12.8 MB
    u16*    h2     = (u16*)   alloc((size_t)NSL * RSTR * 8 * 2);
    u16*    T      = (u16*)   alloc((size_t)NSL * RSTR * 8 * 2);
    float*  partial= (float*) alloc((size_t)NSL * NN * 4);         // 3.2 MB

    (void)hipMemsetAsync(bfill, 0, 128 * sizeof(int), stream);
    k_bin  <<<NB1, 256, 0, stream>>>(ei, bfill, bins);
    k_build<<<NB, 1024, 0, stream>>>(bins, bfill, rowptr, plen, col,
                                     (const float2*)x, dis, xs, T);

    k_l1<<<NAGGB, 256, 0, stream>>>(xs, rowptr, plen, col, dis, W1, b1, h1);

    k_xf <<<NN / 16, 256, 0, stream>>>(h1, W2, T);
    k_agg<false><<<NAGG, 256, 0, stream>>>(T, rowptr, plen, col, dis, b2, nullptr,
                                           h2, nullptr);

    k_xf <<<NN / 16, 256, 0, stream>>>(h2, W3, T);
    k_agg<true ><<<NAGG, 256, 0, stream>>>(T, rowptr, plen, col, dis, b3, Wl,
                                           nullptr, partial);

    k_fin<<<NAGGB, 256, 0, stream>>>(partial, bl, (float*)d_out);
}